// Round 1
// baseline (125.874 us; speedup 1.0000x reference)
//
#include <hip/hip_runtime.h>

#define W      512
#define IMG    (512 * 512)
#define NB     16
#define NPIX   (NB * IMG)

// ---- EDT geometry: 8-row tiles, 8-row apron (exactness guard unchanged) ----
#define TILE_H 8
#define APRON  8
#define LROWS  (TILE_H + 2 * APRON)       // 24
#define BLOCK  256
#define EDT_BLOCKS  (NB * (W / TILE_H))   // 1024

// ---- loss geometry: 16-row slabs ----
#define SLAB_H 16
#define LOSS_BLOCKS (NB * (W / SLAB_H))   // 512
#define GRID   (EDT_BLOCKS + LOSS_BLOCKS) // 1536 == 256 CUs * 6 blocks/CU

struct WS {
    unsigned int vmax[16];        // zeroed each launch; per-batch max int d^2
    float C[16 * 512];            // zeroed each launch; C[b,y] = sum_h t*(x-t)^2
    float rows[16 * 512];         // w_edt[b, h=b, y] (sqrt'd) — fully written by EDT blocks
    float4 partial[LOSS_BLOCKS];  // .x=sum(x-t)^2  .y=sum p*t  .z=sum p  .w=sum t
};

// Fused kernel: blocks [0,1024) compute exact EDT tiles; blocks [1024,1536)
// stream the EDT-independent loss sums. All 1536 blocks are co-resident
// (26.6 KB LDS * 6 = 159.7 KB/CU), so the HBM-bound loss work hides the
// EDT blocks' LDS/ballot latency.
//
// EDT: separable bit-trick. D[r][y] = nearest-zero distance within row r
// (branch-free 128-bit window); best(h,y) = min_{|dh|<=8} dh^2 + D[h+dh][y]^2.
// Searched set is {|dh|<=8, |dx|<=63}; complement d^2 >= 81, so best<=81 exact.
__global__ __launch_bounds__(BLOCK, 6) void fused_kernel(const float* __restrict__ inp,
                                                         const float* __restrict__ tgt,
                                                         WS* __restrict__ ws) {
    __shared__ union {
        struct {
            unsigned long long zm[LROWS][10];   // zeros-mask, cols 1..8 data, 0/9 sentinel
            unsigned short Dd[LROWS][W];        // 24 KB row-profile distances
            unsigned int smax[BLOCK / 64];
        } e;
        struct {
            float4 csh[128];                    // per-y4 column-sum pair-combine
            float4 ssum[BLOCK / 64];
        } l;
    } sh;

    int bid  = blockIdx.x;
    int tid  = threadIdx.x;
    int wave = tid >> 6, lane = tid & 63;

    if (bid >= EDT_BLOCKS) {
        // ================= loss half (independent of EDT) =================
        int lid  = bid - EDT_BLOCKS;      // 0..511
        int b    = lid >> 5;              // 32 slabs per image
        int slab = lid & 31;
        size_t base4 = (size_t)b * (IMG / 4) + (size_t)slab * (SLAB_H * W / 4);
        const float4* x4 = (const float4*)inp + base4;
        const float4* t4 = (const float4*)tgt + base4;

        float s0 = 0.f, s1 = 0.f, s2 = 0.f, s3 = 0.f;
        float4 ct = make_float4(0.f, 0.f, 0.f, 0.f);   // column sums for this thread's y4
        #pragma unroll
        for (int k = 0; k < SLAB_H * W / 4 / BLOCK; ++k) {   // 8
            int i = tid + (k << 8);       // y4 = i & 127 == tid & 127 (fixed per thread)
            float4 xv = x4[i];
            float4 tv = t4[i];
            { float d = xv.x - tv.x; float e2 = d * d; s0 += e2; ct.x += tv.x * e2;
              float p = 1.0f / (1.0f + __expf(-xv.x)); s1 += p * tv.x; s2 += p; s3 += tv.x; }
            { float d = xv.y - tv.y; float e2 = d * d; s0 += e2; ct.y += tv.y * e2;
              float p = 1.0f / (1.0f + __expf(-xv.y)); s1 += p * tv.y; s2 += p; s3 += tv.y; }
            { float d = xv.z - tv.z; float e2 = d * d; s0 += e2; ct.z += tv.z * e2;
              float p = 1.0f / (1.0f + __expf(-xv.z)); s1 += p * tv.z; s2 += p; s3 += tv.z; }
            { float d = xv.w - tv.w; float e2 = d * d; s0 += e2; ct.w += tv.w * e2;
              float p = 1.0f / (1.0f + __expf(-xv.w)); s1 += p * tv.w; s2 += p; s3 += tv.w; }
        }

        // combine the two threads sharing each y4, then one atomicAdd set per y4
        int y4 = tid & 127;
        if (tid < 128) sh.l.csh[tid] = ct;
        __syncthreads();
        if (tid >= 128) {
            float4 o = sh.l.csh[tid - 128];
            float* Cb = ws->C + (b << 9) + (y4 << 2);
            atomicAdd(Cb + 0, o.x + ct.x);
            atomicAdd(Cb + 1, o.y + ct.y);
            atomicAdd(Cb + 2, o.z + ct.z);
            atomicAdd(Cb + 3, o.w + ct.w);
        }

        #pragma unroll
        for (int o = 32; o > 0; o >>= 1) {
            s0 += __shfl_down(s0, o); s1 += __shfl_down(s1, o);
            s2 += __shfl_down(s2, o); s3 += __shfl_down(s3, o);
        }
        if (lane == 0) sh.l.ssum[wave] = make_float4(s0, s1, s2, s3);
        __syncthreads();
        if (tid == 0) {
            float4 a = sh.l.ssum[0];
            #pragma unroll
            for (int i = 1; i < BLOCK / 64; ++i) {
                a.x += sh.l.ssum[i].x; a.y += sh.l.ssum[i].y;
                a.z += sh.l.ssum[i].z; a.w += sh.l.ssum[i].w;
            }
            ws->partial[lid] = a;
        }
        return;
    }

    // ================= EDT half =================
    int b    = bid >> 6;          // 64 tiles per image
    int tile = bid & 63;
    int h0   = tile * TILE_H;
    const float* img = tgt + (size_t)b * IMG;

    auto& zm = sh.e.zm;
    auto& Dd = sh.e.Dd;

    // ---- Phase 1: pack zeros-mask (1 bit/pixel) via ballot, coalesced 256B loads ----
    for (int wi = wave; wi < LROWS * 8; wi += 4) {
        int lr = wi >> 3, wc = wi & 7;
        int gh = h0 - APRON + lr;
        unsigned long long m = 0ULL;
        if (gh >= 0 && gh < W) {
            float v = img[(gh << 9) + (wc << 6) + lane];
            m = __ballot(v == 0.0f);
        }
        if (lane == 0) zm[lr][wc + 1] = m;
    }
    for (int i = tid; i < LROWS; i += BLOCK) { zm[i][0] = 0ULL; zm[i][9] = 0ULL; }
    __syncthreads();

    // ---- Phase 2: 1-D row profiles (branch-free 128-bit window, ctz/clz) ----
    for (int u = wave; u < LROWS * 8; u += 4) {
        int lr = u >> 3, wc = u & 7;
        unsigned long long Wm = zm[lr][wc];
        unsigned long long Wc = zm[lr][wc + 1];
        unsigned long long Wp = zm[lr][wc + 2];
        int off = lane;
        unsigned long long wr = (Wc >> off) | (off ? (Wp << (64 - off)) : 0ULL);
        int dr = wr ? __builtin_ctzll(wr) : 1000;
        unsigned long long vl = off ? ((Wc << (64 - off)) | (Wm >> off)) : Wm;
        int dl = vl ? (1 + __builtin_clzll(vl)) : 1000;
        int d = min(min(dr, dl), 1000);
        Dd[lr][(wc << 6) + lane] = (unsigned short)d;
    }
    __syncthreads();

    // ---- Phase 3: combine, 17 LDS u16 reads/pixel, no divergence ----
    unsigned int bmax = 0;
    for (int k = 0; k < TILE_H * W / BLOCK; ++k) {   // 16 pixels/thread
        int p  = tid + (k << 8);
        int y  = p & (W - 1);
        int hl = p >> 9;
        int lr = hl + APRON;
        int best = 1 << 30;
        #pragma unroll
        for (int dh = -APRON; dh <= APRON; ++dh) {
            int d = Dd[lr + dh][y];
            best = min(best, dh * dh + d * d);
        }
        if (best > 81) {   // exactness fallback — statistically never taken
            int h = h0 + hl;
            best = 100000000;   // matches reference BIG when no zeros exist
            for (int gh = 0; gh < W; ++gh) {
                int dhh = gh - h;
                if (dhh * dhh >= best) continue;
                const float* rp = img + (gh << 9);
                for (int yy = 0; yy < W; ++yy)
                    if (rp[yy] == 0.0f) {
                        int dx = yy - y;
                        best = min(best, dhh * dhh + dx * dx);
                    }
            }
        }
        if (h0 + hl == b) ws->rows[(b << 9) + y] = sqrtf((float)best);
        bmax = max(bmax, (unsigned int)best);
    }

    // block max (int d^2; sqrt is monotone) -> atomicMax
    #pragma unroll
    for (int o = 32; o > 0; o >>= 1) bmax = max(bmax, (unsigned int)__shfl_down(bmax, o));
    if (lane == 0) sh.e.smax[wave] = bmax;
    __syncthreads();
    if (tid == 0) {
        unsigned int bm = sh.e.smax[0];
        #pragma unroll
        for (int i = 1; i < BLOCK / 64; ++i) bm = max(bm, sh.e.smax[i]);
        atomicMax(&ws->vmax[b], bm);
    }
}

// Single-block finalize:
//   wmse_sum = sum_{b,y} C[b,y]*(v_b - rows[b,y]) + EPS_W * E   (all terms >= 0)
//   dice     = 1 - (2*s1 + 1e-6)/(s2 + s3 + 1e-6)
__global__ __launch_bounds__(BLOCK) void final_kernel(const WS* __restrict__ ws,
                                                      float* __restrict__ out) {
    int tid = threadIdx.x;
    __shared__ float vsh[16];
    if (tid < 16) vsh[tid] = sqrtf((float)ws->vmax[tid]);
    __syncthreads();

    double wm = 0.0;
    #pragma unroll
    for (int j = 0; j < (16 * 512) / BLOCK; ++j) {   // 32 cells/thread
        int cell = tid + j * BLOCK;
        wm += (double)ws->C[cell] * (double)(vsh[cell >> 9] - ws->rows[cell]);
    }
    double e = 0, s1 = 0, s2 = 0, s3 = 0;
    #pragma unroll
    for (int j = 0; j < LOSS_BLOCKS / BLOCK; ++j) {  // 2
        float4 p = ws->partial[tid + j * BLOCK];
        e += p.x; s1 += p.y; s2 += p.z; s3 += p.w;
    }

    #pragma unroll
    for (int o = 32; o > 0; o >>= 1) {
        wm += __shfl_down(wm, o); e  += __shfl_down(e, o);
        s1 += __shfl_down(s1, o); s2 += __shfl_down(s2, o); s3 += __shfl_down(s3, o);
    }
    __shared__ double shd[BLOCK / 64][5];
    int lane = tid & 63, wid = tid >> 6;
    if (lane == 0) { shd[wid][0] = wm; shd[wid][1] = e;
                     shd[wid][2] = s1; shd[wid][3] = s2; shd[wid][4] = s3; }
    __syncthreads();
    if (tid == 0) {
        double a0 = 0, a1 = 0, a2 = 0, a3 = 0, a4 = 0;
        #pragma unroll
        for (int i = 0; i < BLOCK / 64; ++i) {
            a0 += shd[i][0]; a1 += shd[i][1]; a2 += shd[i][2]; a3 += shd[i][3]; a4 += shd[i][4];
        }
        double wmse = (a0 + 0.001 * a1) / (double)NPIX;
        out[0] = (float)(0.6 * wmse);
        out[1] = (float)(1.0 - (2.0 * a2 + 1e-6) / (a3 + a4 + 1e-6));
    }
}

extern "C" void kernel_launch(void* const* d_in, const int* in_sizes, int n_in,
                              void* d_out, int out_size, void* d_ws, size_t ws_size,
                              hipStream_t stream) {
    const float* inp = (const float*)d_in[0];
    const float* tgt = (const float*)d_in[1];
    float* out = (float*)d_out;
    WS* ws = (WS*)d_ws;

    // zero vmax + C (contiguous at struct start); rows/partial are fully overwritten
    hipMemsetAsync(d_ws, 0, sizeof(unsigned int) * 16 + sizeof(float) * 16 * 512, stream);
    fused_kernel<<<GRID, BLOCK, 0, stream>>>(inp, tgt, ws);
    final_kernel<<<1, BLOCK, 0, stream>>>(ws, out);
}

// Round 2
// 123.729 us; speedup vs baseline: 1.0173x; 1.0173x over previous
//
#include <hip/hip_runtime.h>

#define W      512
#define IMG    (512 * 512)
#define NB     16
#define NPIX   (NB * IMG)

// ---- EDT geometry: 16-row tiles, 8-row apron (exactness guard unchanged) ----
#define TILE_H 16
#define APRON  8
#define LROWS  (TILE_H + 2 * APRON)       // 32
#define BLOCK  256
#define EDT_BLOCKS  (NB * (W / TILE_H))   // 512

// ---- loss geometry: 16-row slabs ----
#define SLAB_H 16
#define LOSS_BLOCKS (NB * (W / SLAB_H))   // 512
#define GRID   (EDT_BLOCKS + LOSS_BLOCKS) // 1024 == 256 CUs * 4 blocks/CU

struct WS {
    unsigned int vmax[16];        // zeroed each launch; per-batch max int d^2
    float C[16 * 512];            // zeroed each launch; C[b,y] = sum_h t*(x-t)^2
    float rows[16 * 512];         // w_edt[b, h=b, y] (sqrt'd)
    float4 partial[LOSS_BLOCKS];  // .x=sum(x-t)^2  .y=sum p*t  .z=sum p  .w=sum t
};

__device__ __forceinline__ unsigned pk_min_u16(unsigned a, unsigned b) {
    unsigned r; asm("v_pk_min_u16 %0, %1, %2" : "=v"(r) : "v"(a), "v"(b)); return r;
}
__device__ __forceinline__ unsigned pk_max_u16(unsigned a, unsigned b) {
    unsigned r; asm("v_pk_max_u16 %0, %1, %2" : "=v"(r) : "v"(a), "v"(b)); return r;
}

// Exact full-image nearest-zero scan (rare fallback; also handles no-zero case -> BIG)
__device__ int exact_best(const float* __restrict__ img, int h, int y) {
    int best = 100000000;   // reference BIG when no zeros exist
    for (int gh = 0; gh < W; ++gh) {
        int dhh = gh - h;
        if (dhh * dhh >= best) continue;
        const float* rp = img + (gh << 9);
        for (int yy = 0; yy < W; ++yy)
            if (rp[yy] == 0.0f) {
                int dx = yy - y;
                best = min(best, dhh * dhh + dx * dx);
            }
    }
    return best;
}

// Fused kernel, 1024 blocks = exactly 4/CU (LDS 35.4 KB), all co-resident.
// Types interleaved in groups of 8 so each XCD gets a mix of EDT (LDS/VALU-bound)
// and loss (HBM-bound) blocks.
//
// EDT: separable bit-trick. Phase 2 stores CLAMPED d^2 (<=65471) as u16.
// Phase 3 is packed: each thread owns a y-pair; candidate = d2pair + dh2*0x10001
// (no cross-half carry since 65471+64=65535), reduced with v_pk_min_u16.
// Any clamped candidate is >81 and triggers the exact fallback, so results <=81
// are exact and the >81 path recomputes exactly (statistically never taken).
__global__ __launch_bounds__(BLOCK, 4) void fused_kernel(const float* __restrict__ inp,
                                                         const float* __restrict__ tgt,
                                                         WS* __restrict__ ws) {
    __shared__ union {
        struct {
            unsigned long long zm[LROWS][10];   // zeros-mask, cols 1..8 data, 0/9 sentinel
            unsigned short Dd[LROWS][W];        // 32 KB clamped d^2 row profiles
            unsigned int smax[BLOCK / 64];
        } e;
        struct {
            float4 csh[128];
            float4 ssum[BLOCK / 64];
        } l;
    } sh;

    int bid  = blockIdx.x;
    int tid  = threadIdx.x;
    int wave = tid >> 6, lane = tid & 63;
    int type = (bid >> 3) & 1;                    // groups of 8 -> even XCD spread
    int id   = ((bid >> 4) << 3) | (bid & 7);     // 0..511 within type

    if (type) {
        // ================= loss half (independent of EDT) =================
        int b    = id >> 5;              // 32 slabs per image
        int slab = id & 31;
        size_t base4 = (size_t)b * (IMG / 4) + (size_t)slab * (SLAB_H * W / 4);
        const float4* x4 = (const float4*)inp + base4;
        const float4* t4 = (const float4*)tgt + base4;

        float s0 = 0.f, s1 = 0.f, s2 = 0.f, s3 = 0.f;
        float4 ct = make_float4(0.f, 0.f, 0.f, 0.f);   // column sums for this thread's y4
        #pragma unroll
        for (int k = 0; k < SLAB_H * W / 4 / BLOCK; ++k) {   // 8
            int i = tid + (k << 8);       // y4 = i & 127 fixed per thread
            float4 xv = x4[i];
            float4 tv = t4[i];
            { float d = xv.x - tv.x; float e2 = d * d; s0 += e2; ct.x += tv.x * e2;
              float p = 1.0f / (1.0f + __expf(-xv.x)); s1 += p * tv.x; s2 += p; s3 += tv.x; }
            { float d = xv.y - tv.y; float e2 = d * d; s0 += e2; ct.y += tv.y * e2;
              float p = 1.0f / (1.0f + __expf(-xv.y)); s1 += p * tv.y; s2 += p; s3 += tv.y; }
            { float d = xv.z - tv.z; float e2 = d * d; s0 += e2; ct.z += tv.z * e2;
              float p = 1.0f / (1.0f + __expf(-xv.z)); s1 += p * tv.z; s2 += p; s3 += tv.z; }
            { float d = xv.w - tv.w; float e2 = d * d; s0 += e2; ct.w += tv.w * e2;
              float p = 1.0f / (1.0f + __expf(-xv.w)); s1 += p * tv.w; s2 += p; s3 += tv.w; }
        }

        // combine the two threads sharing each y4, then one atomicAdd set per y4
        int y4 = tid & 127;
        if (tid < 128) sh.l.csh[tid] = ct;
        __syncthreads();
        if (tid >= 128) {
            float4 o = sh.l.csh[tid - 128];
            float* Cb = ws->C + (b << 9) + (y4 << 2);
            atomicAdd(Cb + 0, o.x + ct.x);
            atomicAdd(Cb + 1, o.y + ct.y);
            atomicAdd(Cb + 2, o.z + ct.z);
            atomicAdd(Cb + 3, o.w + ct.w);
        }

        #pragma unroll
        for (int o = 32; o > 0; o >>= 1) {
            s0 += __shfl_down(s0, o); s1 += __shfl_down(s1, o);
            s2 += __shfl_down(s2, o); s3 += __shfl_down(s3, o);
        }
        if (lane == 0) sh.l.ssum[wave] = make_float4(s0, s1, s2, s3);
        __syncthreads();
        if (tid == 0) {
            float4 a = sh.l.ssum[0];
            #pragma unroll
            for (int i = 1; i < BLOCK / 64; ++i) {
                a.x += sh.l.ssum[i].x; a.y += sh.l.ssum[i].y;
                a.z += sh.l.ssum[i].z; a.w += sh.l.ssum[i].w;
            }
            ws->partial[id] = a;
        }
        return;
    }

    // ================= EDT half =================
    int b    = id >> 5;          // 32 tiles per image
    int tile = id & 31;
    int h0   = tile * TILE_H;
    const float* img = tgt + (size_t)b * IMG;

    auto& zm = sh.e.zm;
    auto& Dd = sh.e.Dd;

    // ---- Phase 1: pack zeros-mask (1 bit/pixel) via ballot, coalesced 256B loads ----
    for (int wi = wave; wi < LROWS * 8; wi += 4) {
        int lr = wi >> 3, wc = wi & 7;
        int gh = h0 - APRON + lr;
        unsigned long long m = 0ULL;
        if (gh >= 0 && gh < W) {
            float v = img[(gh << 9) + (wc << 6) + lane];
            m = __ballot(v == 0.0f);
        }
        if (lane == 0) zm[lr][wc + 1] = m;
    }
    for (int i = tid; i < LROWS; i += BLOCK) { zm[i][0] = 0ULL; zm[i][9] = 0ULL; }
    __syncthreads();

    // ---- Phase 2: 1-D row profiles; store clamped d^2 as u16 ----
    for (int u = wave; u < LROWS * 8; u += 4) {
        int lr = u >> 3, wc = u & 7;
        unsigned long long Wm = zm[lr][wc];
        unsigned long long Wc = zm[lr][wc + 1];
        unsigned long long Wp = zm[lr][wc + 2];
        int off = lane;
        unsigned long long wr = (Wc >> off) | (off ? (Wp << (64 - off)) : 0ULL);
        int dr = wr ? __builtin_ctzll(wr) : 1000;
        unsigned long long vl = off ? ((Wc << (64 - off)) | (Wm >> off)) : Wm;
        int dl = vl ? (1 + __builtin_clzll(vl)) : 1000;
        int d = min(min(dr, dl), 1000);
        int dd = min(d * d, 65471);              // 65471 + dh^2(<=64) fits u16
        Dd[lr][(wc << 6) + lane] = (unsigned short)dd;
    }
    __syncthreads();

    // ---- Phase 3: packed combine. Each thread owns y = {2*tid, 2*tid+1}. ----
    const unsigned* Dd32 = (const unsigned*)&Dd[0][0];   // 256 u32 per row
    int rowk = (tile == 0) ? b : -1;                     // local k of the rows-row, if any
    unsigned bpk = 0;          // packed max over this thread's pixels
    unsigned rowbest = 0;      // packed best for the rows-row iteration
    for (int k = 0; k < TILE_H; ++k) {
        const unsigned* rowp = Dd32 + k * 256 + tid;     // lr = k + j, j = dh+8 in [0,16]
        unsigned best = 0xFFFFFFFFu;
        #pragma unroll
        for (int j = 0; j <= 16; ++j) {
            unsigned dh2 = (unsigned)((j - 8) * (j - 8));
            best = pk_min_u16(best, rowp[j * 256] + dh2 * 0x00010001u);
        }
        bpk = pk_max_u16(bpk, best);
        if (k == rowk) rowbest = best;
    }

    unsigned rlo = rowbest & 0xFFFFu, rhi = rowbest >> 16;
    unsigned lo = bpk & 0xFFFFu, hi = bpk >> 16;
    unsigned tmax = max(lo, hi);

    // ---- rare exact correction (statistically never taken) ----
    if (__builtin_expect(tmax > 81u, 0)) {
        tmax = 0;
        for (int k = 0; k < TILE_H; ++k) {
            for (int half = 0; half < 2; ++half) {
                int y = (tid << 1) + half;
                int bb = 1 << 30;
                for (int j = 0; j <= 16; ++j)
                    bb = min(bb, (j - 8) * (j - 8) + (int)Dd[k + j][y]);
                if (bb > 81) bb = exact_best(img, h0 + k, y);
                tmax = max(tmax, (unsigned)bb);
                if (k == rowk) { if (half) rhi = (unsigned)bb; else rlo = (unsigned)bb; }
            }
        }
    }

    if (rowk >= 0) {
        ws->rows[(b << 9) + (tid << 1)]     = sqrtf((float)rlo);
        ws->rows[(b << 9) + (tid << 1) + 1] = sqrtf((float)rhi);
    }

    // block max (int d^2; sqrt is monotone) -> atomicMax
    unsigned bmax = tmax;
    #pragma unroll
    for (int o = 32; o > 0; o >>= 1) bmax = max(bmax, (unsigned)__shfl_down(bmax, o));
    if (lane == 0) sh.e.smax[wave] = bmax;
    __syncthreads();
    if (tid == 0) {
        unsigned bm = sh.e.smax[0];
        #pragma unroll
        for (int i = 1; i < BLOCK / 64; ++i) bm = max(bm, sh.e.smax[i]);
        atomicMax(&ws->vmax[b], bm);
    }
}

// Single-block finalize:
//   wmse_sum = sum_{b,y} C[b,y]*(v_b - rows[b,y]) + EPS_W * E   (all terms >= 0)
//   dice     = 1 - (2*s1 + 1e-6)/(s2 + s3 + 1e-6)
__global__ __launch_bounds__(BLOCK) void final_kernel(const WS* __restrict__ ws,
                                                      float* __restrict__ out) {
    int tid = threadIdx.x;
    __shared__ float vsh[16];
    if (tid < 16) vsh[tid] = sqrtf((float)ws->vmax[tid]);
    __syncthreads();

    double wm = 0.0;
    #pragma unroll
    for (int j = 0; j < (16 * 512) / BLOCK; ++j) {   // 32 cells/thread
        int cell = tid + j * BLOCK;
        wm += (double)ws->C[cell] * (double)(vsh[cell >> 9] - ws->rows[cell]);
    }
    double e = 0, s1 = 0, s2 = 0, s3 = 0;
    #pragma unroll
    for (int j = 0; j < LOSS_BLOCKS / BLOCK; ++j) {  // 2
        float4 p = ws->partial[tid + j * BLOCK];
        e += p.x; s1 += p.y; s2 += p.z; s3 += p.w;
    }

    #pragma unroll
    for (int o = 32; o > 0; o >>= 1) {
        wm += __shfl_down(wm, o); e  += __shfl_down(e, o);
        s1 += __shfl_down(s1, o); s2 += __shfl_down(s2, o); s3 += __shfl_down(s3, o);
    }
    __shared__ double shd[BLOCK / 64][5];
    int lane = tid & 63, wid = tid >> 6;
    if (lane == 0) { shd[wid][0] = wm; shd[wid][1] = e;
                     shd[wid][2] = s1; shd[wid][3] = s2; shd[wid][4] = s3; }
    __syncthreads();
    if (tid == 0) {
        double a0 = 0, a1 = 0, a2 = 0, a3 = 0, a4 = 0;
        #pragma unroll
        for (int i = 0; i < BLOCK / 64; ++i) {
            a0 += shd[i][0]; a1 += shd[i][1]; a2 += shd[i][2]; a3 += shd[i][3]; a4 += shd[i][4];
        }
        double wmse = (a0 + 0.001 * a1) / (double)NPIX;
        out[0] = (float)(0.6 * wmse);
        out[1] = (float)(1.0 - (2.0 * a2 + 1e-6) / (a3 + a4 + 1e-6));
    }
}

extern "C" void kernel_launch(void* const* d_in, const int* in_sizes, int n_in,
                              void* d_out, int out_size, void* d_ws, size_t ws_size,
                              hipStream_t stream) {
    const float* inp = (const float*)d_in[0];
    const float* tgt = (const float*)d_in[1];
    float* out = (float*)d_out;
    WS* ws = (WS*)d_ws;

    // zero vmax + C (contiguous at struct start); rows/partial fully overwritten
    hipMemsetAsync(d_ws, 0, sizeof(unsigned int) * 16 + sizeof(float) * 16 * 512, stream);
    fused_kernel<<<GRID, BLOCK, 0, stream>>>(inp, tgt, ws);
    final_kernel<<<1, BLOCK, 0, stream>>>(ws, out);
}

// Round 3
// 96.901 us; speedup vs baseline: 1.2990x; 1.2769x over previous
//
#include <hip/hip_runtime.h>

#define W      512
#define IMG    (512 * 512)
#define NB     16
#define NPIX   (NB * IMG)

// ---- geometry: 512 uniform hybrid blocks of 1024 threads ----
// each block: loss streaming for one 16-row slab + exact EDT for the same tile
#define TILE_H 16
#define APRON  8
#define LROWS  (TILE_H + 2 * APRON)       // 32
#define BLOCK  1024
#define GRID   (NB * (W / TILE_H))        // 512 == 256 CUs * 2 blocks/CU (100% cap)

struct WS {
    unsigned int vmax[16];        // zeroed each launch; per-batch max int d^2
    float C[16 * 512];            // zeroed each launch; C[b,y] = sum_h t*(x-t)^2
    float rows[16 * 512];         // w_edt[b, h=b, y] (sqrt'd)
    float4 partial[GRID];         // .x=sum(x-t)^2  .y=sum p*t  .z=sum p  .w=sum t
};

__device__ __forceinline__ unsigned pk_min_u16(unsigned a, unsigned b) {
    unsigned r; asm("v_pk_min_u16 %0, %1, %2" : "=v"(r) : "v"(a), "v"(b)); return r;
}
__device__ __forceinline__ unsigned pk_max_u16(unsigned a, unsigned b) {
    unsigned r; asm("v_pk_max_u16 %0, %1, %2" : "=v"(r) : "v"(a), "v"(b)); return r;
}

// Exact full-image nearest-zero scan (rare fallback; also handles no-zero case -> BIG)
__device__ int exact_best(const float* __restrict__ img, int h, int y) {
    int best = 100000000;   // reference BIG when no zeros exist
    for (int gh = 0; gh < W; ++gh) {
        int dhh = gh - h;
        if (dhh * dhh >= best) continue;
        const float* rp = img + (gh << 9);
        for (int yy = 0; yy < W; ++yy)
            if (rp[yy] == 0.0f) {
                int dx = yy - y;
                best = min(best, dhh * dhh + dx * dx);
            }
    }
    return best;
}

// EDT: separable bit-trick. Phase 2 stores CLAMPED d^2 (<=65471) as u16.
// Phase 3: each thread owns a y-pair and 4 output rows; loads the 20-row packed
// column once into registers, then 4x17 v_pk_min_u16 with dh^2*0x10001 biases
// (no cross-half carry since 65471+64=65535). Guard: searched set is
// {|dh|<=8, |dx|<=63}; complement d^2 >= 81, so any best<=81 is exact and
// best>81 triggers the exact fallback (statistically never taken).
__global__ __launch_bounds__(BLOCK, 8) void fused_kernel(const float* __restrict__ inp,
                                                         const float* __restrict__ tgt,
                                                         WS* __restrict__ ws) {
    __shared__ union {
        struct {
            unsigned long long zm[LROWS][10];   // zeros-mask, cols 1..8 data, 0/9 sentinel
            unsigned short Dd[LROWS][W];        // 32 KB clamped d^2 row profiles
            unsigned int smax[BLOCK / 64];
        } e;
        struct {
            float4 csh[8][128];                 // per-(group,y4) column sums
            float4 ssum[BLOCK / 64];
        } l;
    } sh;

    int bid  = blockIdx.x;        // 0..511
    int b    = bid >> 5;          // image
    int tile = bid & 31;
    int h0   = tile * TILE_H;
    int tid  = threadIdx.x;
    int wave = tid >> 6, lane = tid & 63;
    const float* img = tgt + (size_t)b * IMG;

    // ================= loss phase: stream this block's 16-row slab =================
    size_t base4 = (size_t)b * (IMG / 4) + (size_t)tile * (TILE_H * W / 4);
    const float4* x4 = (const float4*)inp + base4;
    const float4* t4 = (const float4*)tgt + base4;

    float s0 = 0.f, s1 = 0.f, s2 = 0.f, s3 = 0.f;
    float4 ct = make_float4(0.f, 0.f, 0.f, 0.f);   // column sums for this thread's y4
    #pragma unroll
    for (int k = 0; k < 2; ++k) {                  // 2048 float4 / 1024 threads
        int i = tid + (k << 10);                   // y4 = i & 127 fixed per thread
        float4 xv = x4[i];
        float4 tv = t4[i];
        { float d = xv.x - tv.x; float e2 = d * d; s0 += e2; ct.x += tv.x * e2;
          float p = 1.0f / (1.0f + __expf(-xv.x)); s1 += p * tv.x; s2 += p; s3 += tv.x; }
        { float d = xv.y - tv.y; float e2 = d * d; s0 += e2; ct.y += tv.y * e2;
          float p = 1.0f / (1.0f + __expf(-xv.y)); s1 += p * tv.y; s2 += p; s3 += tv.y; }
        { float d = xv.z - tv.z; float e2 = d * d; s0 += e2; ct.z += tv.z * e2;
          float p = 1.0f / (1.0f + __expf(-xv.z)); s1 += p * tv.z; s2 += p; s3 += tv.z; }
        { float d = xv.w - tv.w; float e2 = d * d; s0 += e2; ct.w += tv.w * e2;
          float p = 1.0f / (1.0f + __expf(-xv.w)); s1 += p * tv.w; s2 += p; s3 += tv.w; }
    }
    sh.l.csh[tid >> 7][tid & 127] = ct;
    #pragma unroll
    for (int o = 32; o > 0; o >>= 1) {
        s0 += __shfl_down(s0, o); s1 += __shfl_down(s1, o);
        s2 += __shfl_down(s2, o); s3 += __shfl_down(s3, o);
    }
    if (lane == 0) sh.l.ssum[wave] = make_float4(s0, s1, s2, s3);
    __syncthreads();

    if (tid < 128) {
        float4 a = sh.l.csh[0][tid];
        #pragma unroll
        for (int g = 1; g < 8; ++g) {
            float4 c = sh.l.csh[g][tid];
            a.x += c.x; a.y += c.y; a.z += c.z; a.w += c.w;
        }
        float* Cb = ws->C + (b << 9) + (tid << 2);
        atomicAdd(Cb + 0, a.x);
        atomicAdd(Cb + 1, a.y);
        atomicAdd(Cb + 2, a.z);
        atomicAdd(Cb + 3, a.w);
    } else if (tid == 128) {
        float4 a = sh.l.ssum[0];
        #pragma unroll
        for (int i = 1; i < BLOCK / 64; ++i) {
            a.x += sh.l.ssum[i].x; a.y += sh.l.ssum[i].y;
            a.z += sh.l.ssum[i].z; a.w += sh.l.ssum[i].w;
        }
        ws->partial[bid] = a;
    }
    __syncthreads();   // csh reads done before zm/Dd overwrite the union

    // ================= EDT phase 1: pack zeros-mask via ballot =================
    // core rows were just read by the loss phase -> L1/L2 hits
    auto& zm = sh.e.zm;
    auto& Dd = sh.e.Dd;
    for (int wi = wave; wi < LROWS * 8; wi += BLOCK / 64) {   // 16 units/wave
        int lr = wi >> 3, wc = wi & 7;
        int gh = h0 - APRON + lr;
        unsigned long long m = 0ULL;
        if (gh >= 0 && gh < W) {
            float v = img[(gh << 9) + (wc << 6) + lane];
            m = __ballot(v == 0.0f);
        }
        if (lane == 0) zm[lr][wc + 1] = m;
    }
    if (tid < LROWS) { zm[tid][0] = 0ULL; zm[tid][9] = 0ULL; }
    __syncthreads();

    // ================= EDT phase 2: row profiles, clamped d^2 as u16 =================
    for (int u = wave; u < LROWS * 8; u += BLOCK / 64) {
        int lr = u >> 3, wc = u & 7;
        unsigned long long Wm = zm[lr][wc];
        unsigned long long Wc = zm[lr][wc + 1];
        unsigned long long Wp = zm[lr][wc + 2];
        int off = lane;
        unsigned long long wr = (Wc >> off) | (off ? (Wp << (64 - off)) : 0ULL);
        int dr = wr ? __builtin_ctzll(wr) : 1000;
        unsigned long long vl = off ? ((Wc << (64 - off)) | (Wm >> off)) : Wm;
        int dl = vl ? (1 + __builtin_clzll(vl)) : 1000;
        int d = min(min(dr, dl), 1000);
        int dd = min(d * d, 65471);              // 65471 + dh^2(<=64) fits u16
        Dd[lr][(wc << 6) + lane] = (unsigned short)dd;
    }
    __syncthreads();

    // ================= EDT phase 3: register-column packed combine =================
    // thread -> y-pair p = tid & 255, output-row group q = tid >> 8 (rows 4q..4q+3)
    int p = tid & 255;
    int q = tid >> 8;
    const unsigned* Dd32 = (const unsigned*)&Dd[0][0];   // 256 u32 per row
    const unsigned* basep = Dd32 + (q << 10) + p;        // row 4q, column p
    unsigned col[20];
    #pragma unroll
    for (int j = 0; j < 20; ++j) col[j] = basep[j * 256];

    unsigned best[4];
    #pragma unroll
    for (int m = 0; m < 4; ++m) {
        unsigned bb = 0xFFFFFFFFu;
        #pragma unroll
        for (int j = 0; j <= 16; ++j) {
            unsigned dh2 = (unsigned)((j - 8) * (j - 8));
            bb = pk_min_u16(bb, col[m + j] + dh2 * 0x00010001u);
        }
        best[m] = bb;
    }
    unsigned bpk = pk_max_u16(pk_max_u16(best[0], best[1]), pk_max_u16(best[2], best[3]));
    unsigned tmax = max(bpk & 0xFFFFu, bpk >> 16);

    // ---- rare exact correction (statistically never taken) ----
    if (__builtin_expect(tmax > 81u, 0)) {
        tmax = 0;
        for (int m = 0; m < 4; ++m) {
            int k = (q << 2) + m;
            unsigned nb = 0;
            for (int half = 0; half < 2; ++half) {
                int y = (p << 1) + half;
                int bb = 1 << 30;
                for (int j = 0; j <= 16; ++j)
                    bb = min(bb, (j - 8) * (j - 8) + (int)Dd[k + j][y]);
                if (bb > 81) bb = exact_best(img, h0 + k, y);   // clamped -> true >81 -> exact
                tmax = max(tmax, (unsigned)bb);
                nb |= ((unsigned)bb & 0xFFFFu) << (half * 16);
            }
            best[m] = nb;
        }
    }

    // rows[b, h=b, :] lives in tile 0, local row k=b
    if (tile == 0 && q == (b >> 2)) {
        unsigned rb = best[b & 3];
        ws->rows[(b << 9) + (p << 1)]     = sqrtf((float)(rb & 0xFFFFu));
        ws->rows[(b << 9) + (p << 1) + 1] = sqrtf((float)(rb >> 16));
    }

    // block max (int d^2; sqrt is monotone) -> atomicMax
    #pragma unroll
    for (int o = 32; o > 0; o >>= 1) tmax = max(tmax, (unsigned)__shfl_down(tmax, o));
    if (lane == 0) sh.e.smax[wave] = tmax;
    __syncthreads();
    if (tid == 0) {
        unsigned bm = sh.e.smax[0];
        #pragma unroll
        for (int i = 1; i < BLOCK / 64; ++i) bm = max(bm, sh.e.smax[i]);
        atomicMax(&ws->vmax[b], bm);
    }
}

// Single-block finalize:
//   wmse_sum = sum_{b,y} C[b,y]*(v_b - rows[b,y]) + EPS_W * E   (all terms >= 0)
//   dice     = 1 - (2*s1 + 1e-6)/(s2 + s3 + 1e-6)
#define FBLOCK 256
__global__ __launch_bounds__(FBLOCK) void final_kernel(const WS* __restrict__ ws,
                                                       float* __restrict__ out) {
    int tid = threadIdx.x;
    __shared__ float vsh[16];
    if (tid < 16) vsh[tid] = sqrtf((float)ws->vmax[tid]);
    __syncthreads();

    double wm = 0.0;
    #pragma unroll
    for (int j = 0; j < (16 * 512) / FBLOCK; ++j) {   // 32 cells/thread
        int cell = tid + j * FBLOCK;
        wm += (double)ws->C[cell] * (double)(vsh[cell >> 9] - ws->rows[cell]);
    }
    double e = 0, s1 = 0, s2 = 0, s3 = 0;
    #pragma unroll
    for (int j = 0; j < GRID / FBLOCK; ++j) {         // 2
        float4 p = ws->partial[tid + j * FBLOCK];
        e += p.x; s1 += p.y; s2 += p.z; s3 += p.w;
    }

    #pragma unroll
    for (int o = 32; o > 0; o >>= 1) {
        wm += __shfl_down(wm, o); e  += __shfl_down(e, o);
        s1 += __shfl_down(s1, o); s2 += __shfl_down(s2, o); s3 += __shfl_down(s3, o);
    }
    __shared__ double shd[FBLOCK / 64][5];
    int lane = tid & 63, wid = tid >> 6;
    if (lane == 0) { shd[wid][0] = wm; shd[wid][1] = e;
                     shd[wid][2] = s1; shd[wid][3] = s2; shd[wid][4] = s3; }
    __syncthreads();
    if (tid == 0) {
        double a0 = 0, a1 = 0, a2 = 0, a3 = 0, a4 = 0;
        #pragma unroll
        for (int i = 0; i < FBLOCK / 64; ++i) {
            a0 += shd[i][0]; a1 += shd[i][1]; a2 += shd[i][2]; a3 += shd[i][3]; a4 += shd[i][4];
        }
        double wmse = (a0 + 0.001 * a1) / (double)NPIX;
        out[0] = (float)(0.6 * wmse);
        out[1] = (float)(1.0 - (2.0 * a2 + 1e-6) / (a3 + a4 + 1e-6));
    }
}

extern "C" void kernel_launch(void* const* d_in, const int* in_sizes, int n_in,
                              void* d_out, int out_size, void* d_ws, size_t ws_size,
                              hipStream_t stream) {
    const float* inp = (const float*)d_in[0];
    const float* tgt = (const float*)d_in[1];
    float* out = (float*)d_out;
    WS* ws = (WS*)d_ws;

    // zero vmax + C (contiguous at struct start); rows/partial fully overwritten
    hipMemsetAsync(d_ws, 0, sizeof(unsigned int) * 16 + sizeof(float) * 16 * 512, stream);
    fused_kernel<<<GRID, BLOCK, 0, stream>>>(inp, tgt, ws);
    final_kernel<<<1, FBLOCK, 0, stream>>>(ws, out);
}